// Round 11
// baseline (3744.419 us; speedup 1.0000x reference)
//
#include <hip/hip_runtime.h>
#include <stdint.h>

// 3-layer LSTM (H=64, B=256, S=4096, DIN=1) + linear head.
// R11: one block/batch (256 blocks), block = 4 waves (1/SIMD):
//   wave l (0..2): layer-l recurrence ENTIRELY within the wave. Per step:
//     gates(256) = Whh.h as 32 mfma_f32_16x16x32_f16 (A = h replicated over
//     rows, 2 broadcast ds_read_b128; B = phi-permuted Whh frags, parked in
//     AGPRs and read natively by MFMA). phi: chunk c covers gate c&3, units
//     (c>>2)*16+n  =>  lane (Q,n) owns unit u=Q*16+n, gates at acc[4Q+g][0]
//     (compile-time reg, 12 cndmask). No cross-wave sync inside the 16-step
//     run; __syncthreads only every 16 steps (261 barriers vs 4134 in R10).
//   wave 3: batched Wih1/Wih2 GEMMs into Xg (R10-verified layout) + y head.
// Skews: L0@[16r,16r+16), L1 lags 32, L2 lags 64, head lags 80.

#define SQ 4096
#define HH 64
#define NB 256
#define RP 72   // padded ring row (halfs): 144B stride -> helper reads 2-way

typedef _Float16 f16x8 __attribute__((ext_vector_type(8)));
typedef float    f32x4 __attribute__((ext_vector_type(4)));

__device__ __forceinline__ f16x8 bcf(uint4 v) { return __builtin_bit_cast(f16x8, v); }

__device__ __forceinline__ float fsigm(float x) {
    return __builtin_amdgcn_rcpf(1.f + __builtin_amdgcn_exp2f(-1.44269504f * x));
}
__device__ __forceinline__ float ftanh(float x) {   // safe for |x| <= ~40
    float e = __builtin_amdgcn_exp2f(-2.88539008f * x);
    return (1.f - e) * __builtin_amdgcn_rcpf(1.f + e);
}

// ---- prep: fp32 weights -> packed fp16 in ws (regions of 16384 halfs) ----
// region 0: Whh0 | 1: Wih1 | 2: Whh1 | 3: Wih2 | 4: Whh2
__global__ void prep_weights(const float* __restrict__ Whh0,
                             const float* __restrict__ Wih1,
                             const float* __restrict__ Whh1,
                             const float* __restrict__ Wih2,
                             const float* __restrict__ Whh2,
                             uint16_t* __restrict__ wsh) {
    const int i = blockIdx.x * 256 + threadIdx.x;        // 0..81919
    const int region = i >> 14;
    const int off = i & 16383;
    const float* src = (region == 0) ? Whh0 : (region == 1) ? Wih1
                     : (region == 2) ? Whh1 : (region == 3) ? Wih2 : Whh2;
    _Float16 v = (_Float16)src[off];
    wsh[i] = __builtin_bit_cast(uint16_t, v);
}

__global__ __launch_bounds__(256, 1) void lstm3_fused(
    const float* __restrict__ x,
    const float* __restrict__ Wih0,
    const float* __restrict__ bih0, const float* __restrict__ bhh0,
    const float* __restrict__ bih1, const float* __restrict__ bhh1,
    const float* __restrict__ bih2, const float* __restrict__ bhh2,
    const float* __restrict__ Wlin, const float* __restrict__ blin,
    const uint16_t* __restrict__ wsh,
    float* __restrict__ out)
{
    const int b    = blockIdx.x;
    const int tid  = threadIdx.x;
    const int wv   = tid >> 6;         // 0,1,2 = layer recurrence; 3 = helper
    const int lane = tid & 63;
    const int n15  = lane & 15;
    const int Q    = lane >> 4;
    const int u    = Q * 16 + n15;     // unit owned by this lane

    __shared__ __align__(16) float xrow[SQ];               // 16 KB
    __shared__ __align__(16) _Float16 ring[3][32][RP];     // 13.5 KB
    __shared__ __align__(16) _Float16 Xg[2][2][16][256];   // 32 KB

    for (int i = tid; i < SQ; i += 256) xrow[i] = x[b * SQ + i];
    for (int i = tid; i < 3 * 32 * RP; i += 256) ((_Float16*)ring)[i] = (_Float16)0.f;

    if (wv < 3) {
        // ================= recurrence wave (layer l) =================
        const int l = wv;
        const uint16_t* wr = wsh + ((l == 0) ? 0 : (l == 1) ? 2 : 4) * 16384;
        f16x8 Bw[16][2];
#pragma unroll
        for (int c = 0; c < 16; ++c) {
            const int row = (c & 3) * 64 + (c >> 2) * 16 + n15;   // phi(c,n)
#pragma unroll
            for (int kh = 0; kh < 2; ++kh)
                Bw[c][kh] = bcf(*(const uint4*)(wr + row * 64 + kh * 32 + Q * 8));
        }
        const float* bihp = (l == 0) ? bih0 : (l == 1) ? bih1 : bih2;
        const float* bhhp = (l == 0) ? bhh0 : (l == 1) ? bhh1 : bhh2;
        float bias[4], wx[4];
#pragma unroll
        for (int g = 0; g < 4; ++g) {
            bias[g] = bihp[g * 64 + u] + bhhp[g * 64 + u];
            wx[g]   = (l == 0) ? Wih0[g * 64 + u] : 0.f;
        }
        const bool q0 = (Q == 0), q1 = (Q == 1), q2 = (Q == 2);
        float cc = 0.f;

        __syncthreads();

        for (int r = 0; r < 261; ++r) {
            const int start = 16 * r - 32 * l;
            if (start >= 0 && start < SQ) {
                const _Float16* xgp = &Xg[(l > 0) ? (l - 1) : 0][r & 1][0][0];
                for (int s = 0; s < 16; ++s) {
                    const int t = start + s;
                    const _Float16* hr = &ring[l][(t - 1) & 31][0];
                    f16x8 a1 = bcf(*(const uint4*)(hr + Q * 8));        // h[8Q..]
                    f16x8 a2 = bcf(*(const uint4*)(hr + 32 + Q * 8));   // h[32+8Q..]
                    f32x4 acc[16];
#pragma unroll
                    for (int c = 0; c < 16; ++c) {
                        f32x4 z = {0.f, 0.f, 0.f, 0.f};
                        z = __builtin_amdgcn_mfma_f32_16x16x32_f16(a1, Bw[c][0], z, 0, 0, 0);
                        acc[c] = __builtin_amdgcn_mfma_f32_16x16x32_f16(a2, Bw[c][1], z, 0, 0, 0);
                    }
                    float gate[4];
#pragma unroll
                    for (int g = 0; g < 4; ++g) {
                        float v = q0 ? acc[g][0] : q1 ? acc[4 + g][0]
                                : q2 ? acc[8 + g][0] : acc[12 + g][0];
                        v += bias[g];
                        if (l == 0) v += wx[g] * xrow[t];
                        else        v += (float)xgp[s * 256 + g * 64 + u];
                        gate[g] = v;
                    }
                    const float si = fsigm(gate[0]);
                    const float sf = fsigm(gate[1]);
                    const float tg = ftanh(gate[2]);
                    const float so = fsigm(gate[3]);
                    cc = sf * cc + si * tg;
                    const float tc = fminf(fmaxf(cc, -15.f), 15.f);
                    const float h  = so * ftanh(tc);
                    ring[l][t & 31][u] = (_Float16)h;
                    if (t == SQ - 1) {
                        out[NB * SQ + l * NB * HH + b * HH + u] = h;
                        out[NB * SQ + 3 * NB * HH + l * NB * HH + b * HH + u] = cc;
                    }
                }
            }
            __syncthreads();
        }
    } else {
        // ================= helper wave =================
        f16x8 B1[16][2], B2[16][2];
#pragma unroll
        for (int c = 0; c < 16; ++c)
#pragma unroll
            for (int kh = 0; kh < 2; ++kh) {
                B1[c][kh] = bcf(*(const uint4*)(wsh + 1 * 16384 + (16 * c + n15) * 64 + kh * 32 + Q * 8));
                B2[c][kh] = bcf(*(const uint4*)(wsh + 3 * 16384 + (16 * c + n15) * 64 + kh * 32 + Q * 8));
            }
        f16x8 Bl[2];
#pragma unroll
        for (int kh = 0; kh < 2; ++kh)
#pragma unroll
            for (int j = 0; j < 8; ++j)
                Bl[kh][j] = (_Float16)Wlin[kh * 32 + Q * 8 + j];
        const float blv = blin[0];

        __syncthreads();

        for (int r = 0; r < 261; ++r) {
            if (r >= 1 && r <= 256) {          // Xg1 = h0-window x Wih1^T
                const int t0 = 16 * (r - 1);
                const int buf = (r - 1) & 1;
                const _Float16* hr = &ring[0][(t0 + n15) & 31][0];
                f16x8 a1 = bcf(*(const uint4*)(hr + Q * 8));
                f16x8 a2 = bcf(*(const uint4*)(hr + 32 + Q * 8));
#pragma unroll
                for (int c = 0; c < 16; ++c) {
                    f32x4 z = {0.f, 0.f, 0.f, 0.f};
                    z = __builtin_amdgcn_mfma_f32_16x16x32_f16(a1, B1[c][0], z, 0, 0, 0);
                    z = __builtin_amdgcn_mfma_f32_16x16x32_f16(a2, B1[c][1], z, 0, 0, 0);
#pragma unroll
                    for (int rr = 0; rr < 4; ++rr)
                        Xg[0][buf][4 * Q + rr][16 * c + n15] = (_Float16)z[rr];
                }
            }
            if (r >= 3 && r <= 258) {          // Xg2 = h1-window x Wih2^T
                const int t0 = 16 * r - 48;
                const int buf = (r - 3) & 1;
                const _Float16* hr = &ring[1][(t0 + n15) & 31][0];
                f16x8 a1 = bcf(*(const uint4*)(hr + Q * 8));
                f16x8 a2 = bcf(*(const uint4*)(hr + 32 + Q * 8));
#pragma unroll
                for (int c = 0; c < 16; ++c) {
                    f32x4 z = {0.f, 0.f, 0.f, 0.f};
                    z = __builtin_amdgcn_mfma_f32_16x16x32_f16(a1, B2[c][0], z, 0, 0, 0);
                    z = __builtin_amdgcn_mfma_f32_16x16x32_f16(a2, B2[c][1], z, 0, 0, 0);
#pragma unroll
                    for (int rr = 0; rr < 4; ++rr)
                        Xg[1][buf][4 * Q + rr][16 * c + n15] = (_Float16)z[rr];
                }
            }
            if (r >= 5 && r <= 260) {          // head: y = Wlin . h2 + blin
                const int t0 = 16 * r - 80;
                const _Float16* hr = &ring[2][(t0 + n15) & 31][0];
                f16x8 a1 = bcf(*(const uint4*)(hr + Q * 8));
                f16x8 a2 = bcf(*(const uint4*)(hr + 32 + Q * 8));
                f32x4 z = {0.f, 0.f, 0.f, 0.f};
                z = __builtin_amdgcn_mfma_f32_16x16x32_f16(a1, Bl[0], z, 0, 0, 0);
                z = __builtin_amdgcn_mfma_f32_16x16x32_f16(a2, Bl[1], z, 0, 0, 0);
                if (n15 == 0) {
#pragma unroll
                    for (int rr = 0; rr < 4; ++rr)
                        out[b * SQ + t0 + 4 * Q + rr] = z[rr] + blv;
                }
            }
            __syncthreads();
        }
    }
}

extern "C" void kernel_launch(void* const* d_in, const int* in_sizes, int n_in,
                              void* d_out, int out_size, void* d_ws, size_t ws_size,
                              hipStream_t stream) {
    const float* x    = (const float*)d_in[0];
    const float* Wih0 = (const float*)d_in[1];
    const float* Whh0 = (const float*)d_in[2];
    const float* bih0 = (const float*)d_in[3];
    const float* bhh0 = (const float*)d_in[4];
    const float* Wih1 = (const float*)d_in[5];
    const float* Whh1 = (const float*)d_in[6];
    const float* bih1 = (const float*)d_in[7];
    const float* bhh1 = (const float*)d_in[8];
    const float* Wih2 = (const float*)d_in[9];
    const float* Whh2 = (const float*)d_in[10];
    const float* bih2 = (const float*)d_in[11];
    const float* bhh2 = (const float*)d_in[12];
    const float* Wlin = (const float*)d_in[13];
    const float* blin = (const float*)d_in[14];
    float* out = (float*)d_out;
    uint16_t* wsh = (uint16_t*)d_ws;

    prep_weights<<<320, 256, 0, stream>>>(Whh0, Wih1, Whh1, Wih2, Whh2, wsh);
    lstm3_fused<<<NB, 256, 0, stream>>>(x, Wih0, bih0, bhh0,
                                        bih1, bhh1, bih2, bhh2,
                                        Wlin, blin, wsh, out);
}